// Round 2
// baseline (9581.216 us; speedup 1.0000x reference)
//
#include <hip/hip_runtime.h>
#include <math.h>

#define SS 512
#define BB 64
#define II 512
#define HH 512
#define MM (SS*BB)

// ---------------------------------------------------------------------------
// Input projection: C[m, j] = sum_k X[m,k] * W1[j,k] + b1[j]
// Tiled fp32 GEMM: 64x64 tile, BK=16, 256 threads, 4x4 per thread.
// Writes xp directly into d_out's h_seq region (consumed in place later).
// ---------------------------------------------------------------------------
__global__ __launch_bounds__(256) void k_ingemm(const float* __restrict__ X,
                                                const float* __restrict__ W1,
                                                const float* __restrict__ b1,
                                                float* __restrict__ C) {
    __shared__ float As[16][64];
    __shared__ float Bs[16][64];
    const int bm = blockIdx.x * 64, bn = blockIdx.y * 64;
    const int tid = threadIdx.x;
    const int tm = (tid >> 4) << 2, tn = (tid & 15) << 2;
    const int lr = tid >> 2, lq = (tid & 3) << 2;
    float acc[4][4] = {};
    const float* Xp = X + (size_t)(bm + lr) * II + lq;
    const float* Wp = W1 + (size_t)(bn + lr) * II + lq;
    for (int kb = 0; kb < II; kb += 16) {
        float4 a = *(const float4*)(Xp + kb);
        float4 w = *(const float4*)(Wp + kb);
        As[lq + 0][lr] = a.x; As[lq + 1][lr] = a.y;
        As[lq + 2][lr] = a.z; As[lq + 3][lr] = a.w;
        Bs[lq + 0][lr] = w.x; Bs[lq + 1][lr] = w.y;
        Bs[lq + 2][lr] = w.z; Bs[lq + 3][lr] = w.w;
        __syncthreads();
#pragma unroll
        for (int k = 0; k < 16; k++) {
            float4 av = *(const float4*)&As[k][tm];
            float4 bv = *(const float4*)&Bs[k][tn];
            float aa[4] = {av.x, av.y, av.z, av.w};
            float bb[4] = {bv.x, bv.y, bv.z, bv.w};
#pragma unroll
            for (int i = 0; i < 4; i++)
#pragma unroll
                for (int j = 0; j < 4; j++)
                    acc[i][j] = fmaf(aa[i], bb[j], acc[i][j]);
        }
        __syncthreads();
    }
#pragma unroll
    for (int i = 0; i < 4; i++) {
        float4 bv = *(const float4*)&b1[bn + tn];
        float4 o;
        o.x = acc[i][0] + bv.x; o.y = acc[i][1] + bv.y;
        o.z = acc[i][2] + bv.z; o.w = acc[i][3] + bv.w;
        *(float4*)&C[(size_t)(bm + tm + i) * HH + bn + tn] = o;
    }
}

// ---------------------------------------------------------------------------
// Recurrence with W2 fully register-resident.
// 64 WGs (one per batch element), 1024 threads = 16 waves.
// Thread t: j = t & 511 (output column), kh = t >> 9 (k-half 0/1).
// Holds W2[j][kh*256 .. kh*256+255] in 256 VGPRs (static unrolled indexing).
// Per step: 256 FMAs vs broadcast LDS reads of h, LDS combine of the two
// k-halves, tanh, in-place xp->h overwrite in d_out. 2 barriers/step.
// ---------------------------------------------------------------------------
__global__ __launch_bounds__(1024) void k_rec2(const float* __restrict__ W2,
                                               const float* __restrict__ b2,
                                               float* __restrict__ out,
                                               float* __restrict__ hlast) {
    const int b = blockIdx.x;
    const int t = threadIdx.x;
    const int j = t & 511;
    const int kh = t >> 9;  // 0 or 1
    __shared__ float hs[HH];
    __shared__ float partB[HH];

    // One-time load of this thread's W2 slice into registers.
    float w[256];
    const float* wrow = W2 + (size_t)j * HH + (kh << 8);
#pragma unroll
    for (int i = 0; i < 64; i++)
        *(float4*)&w[i * 4] = *(const float4*)(wrow + i * 4);

    const float bias = (kh == 0) ? b2[j] : 0.f;
    if (t < HH) hs[t] = 0.f;
    float* po = out + (size_t)b * HH + j;
    __syncthreads();

    for (int step = 0; step < SS; ++step) {
        // Issue xp load early; consumed after the FMA loop (latency hidden).
        float xpv = 0.f;
        if (kh == 0) xpv = po[0];

        float acc = 0.f;
        const float* hp = &hs[kh << 8];
#pragma unroll
        for (int k = 0; k < 256; k += 4) {
            float4 hv = *(const float4*)&hp[k];  // wave-uniform broadcast
            acc = fmaf(w[k + 0], hv.x, acc);
            acc = fmaf(w[k + 1], hv.y, acc);
            acc = fmaf(w[k + 2], hv.z, acc);
            acc = fmaf(w[k + 3], hv.w, acc);
        }
        if (kh == 1) partB[j] = acc;
        __syncthreads();  // partB visible; all hs reads complete
        if (kh == 0) {
            float z = acc + partB[j] + bias + xpv;
            float hn = tanhf(z);
            hs[j] = hn;
            po[0] = hn;
        }
        __syncthreads();  // hs update visible for next step
        po += BB * HH;
    }
    if (kh == 0) hlast[(size_t)b * HH + j] = hs[j];
}

extern "C" void kernel_launch(void* const* d_in, const int* in_sizes, int n_in,
                              void* d_out, int out_size, void* d_ws, size_t ws_size,
                              hipStream_t stream) {
    const float* x  = (const float*)d_in[0];
    const float* W1 = (const float*)d_in[1];
    const float* b1 = (const float*)d_in[2];
    const float* W2 = (const float*)d_in[3];
    const float* b2 = (const float*)d_in[4];
    float* out = (float*)d_out;

    k_ingemm<<<dim3(MM / 64, HH / 64), 256, 0, stream>>>(x, W1, b1, out);
    k_rec2<<<BB, 1024, 0, stream>>>(W2, b2, out, out + (size_t)SS * BB * HH);
}

// Round 4
// 1740.698 us; speedup vs baseline: 5.5042x; 5.5042x over previous
//
#include <hip/hip_runtime.h>
#include <math.h>

#define SS 512
#define BB 64
#define II 512
#define HH 512
#define MM (SS*BB)

typedef _Float16 h2 __attribute__((ext_vector_type(2)));

__device__ __forceinline__ float fdot2(h2 a, h2 b, float c) {
    return __builtin_amdgcn_fdot2(a, b, c, false);
}
__device__ __forceinline__ h2 bc_h2(unsigned int u) {
    return __builtin_bit_cast(h2, u);
}
__device__ __forceinline__ unsigned int bc_u(h2 v) {
    return __builtin_bit_cast(unsigned int, v);
}
// cvt_pkrtz returns __fp16 ext_vector(2); bit_cast it to our h2.
__device__ __forceinline__ h2 pk(float x, float y) {
    return __builtin_bit_cast(h2, __builtin_amdgcn_cvt_pkrtz(x, y));
}

// ---------------------------------------------------------------------------
// Input projection: C[m, j] = sum_k X[m,k] * W1[j,k] + b1[j]  (fp32 VALU GEMM)
// Writes xp directly into d_out's h_seq region (consumed in place later).
// ---------------------------------------------------------------------------
__global__ __launch_bounds__(256) void k_ingemm(const float* __restrict__ X,
                                                const float* __restrict__ W1,
                                                const float* __restrict__ b1,
                                                float* __restrict__ C) {
    __shared__ float As[16][64];
    __shared__ float Bs[16][64];
    const int bm = blockIdx.x * 64, bn = blockIdx.y * 64;
    const int tid = threadIdx.x;
    const int tm = (tid >> 4) << 2, tn = (tid & 15) << 2;
    const int lr = tid >> 2, lq = (tid & 3) << 2;
    float acc[4][4] = {};
    const float* Xp = X + (size_t)(bm + lr) * II + lq;
    const float* Wp = W1 + (size_t)(bn + lr) * II + lq;
    for (int kb = 0; kb < II; kb += 16) {
        float4 a = *(const float4*)(Xp + kb);
        float4 w = *(const float4*)(Wp + kb);
        As[lq + 0][lr] = a.x; As[lq + 1][lr] = a.y;
        As[lq + 2][lr] = a.z; As[lq + 3][lr] = a.w;
        Bs[lq + 0][lr] = w.x; Bs[lq + 1][lr] = w.y;
        Bs[lq + 2][lr] = w.z; Bs[lq + 3][lr] = w.w;
        __syncthreads();
#pragma unroll
        for (int k = 0; k < 16; k++) {
            float4 av = *(const float4*)&As[k][tm];
            float4 bv = *(const float4*)&Bs[k][tn];
            float aa[4] = {av.x, av.y, av.z, av.w};
            float bb[4] = {bv.x, bv.y, bv.z, bv.w};
#pragma unroll
            for (int i = 0; i < 4; i++)
#pragma unroll
                for (int j = 0; j < 4; j++)
                    acc[i][j] = fmaf(aa[i], bb[j], acc[i][j]);
        }
        __syncthreads();
    }
#pragma unroll
    for (int i = 0; i < 4; i++) {
        float4 bv = *(const float4*)&b1[bn + tn];
        float4 o;
        o.x = acc[i][0] + bv.x; o.y = acc[i][1] + bv.y;
        o.z = acc[i][2] + bv.z; o.w = acc[i][3] + bv.w;
        *(float4*)&C[(size_t)(bm + tm + i) * HH + bn + tn] = o;
    }
}

// ---------------------------------------------------------------------------
// Recurrence, W2 CU-resident in f16:
//   64 WGs (one per batch element) x 512 threads (8 waves).
//   Thread t owns output column t = row t of W2 (z[t] = sum_k W2[t][k]*h[k]).
//   k in [0,384): 192 packed f16-pairs in VGPRs (192 VGPRs; budget 256 via
//                 __launch_bounds__(512,2) -> 2 waves/SIMD).
//   k in [384,512): 128 KB LDS slice wlds[g][col] (uint4 = 4 pairs); per-lane
//                 reads are consecutive-16B -> conflict-free.
//   h: 512 f16 in LDS, read as wave-uniform uint4 broadcasts (free).
//   Math: v_dot2_f32_f16 (2 MAC/instr, f32 accum). xp read early (latency
//   hidden under the dot chain), h overwrites xp in d_out in place.
// ---------------------------------------------------------------------------
__global__ __launch_bounds__(512, 2) void k_rec3(const float* __restrict__ W2,
                                                 const float* __restrict__ b2,
                                                 float* __restrict__ out,
                                                 float* __restrict__ hlast) {
    const int b = blockIdx.x;
    const int t = threadIdx.x;
    __shared__ uint4 wlds[16][512];                 // 128 KB
    __shared__ __align__(16) _Float16 hsmem[HH];    // 1 KB
    const uint4* hs4 = (const uint4*)hsmem;

    // One-time: load W2 row t, convert to packed f16 pairs.
    h2 wr[192];
    const float2* wrow = (const float2*)(W2 + (size_t)t * HH);
#pragma unroll
    for (int i = 0; i < 192; i++) {
        float2 f = wrow[i];
        wr[i] = pk(f.x, f.y);
    }
#pragma unroll
    for (int g = 0; g < 16; g++) {
        float2 f0 = wrow[192 + 4 * g + 0];
        float2 f1 = wrow[192 + 4 * g + 1];
        float2 f2 = wrow[192 + 4 * g + 2];
        float2 f3 = wrow[192 + 4 * g + 3];
        uint4 u;
        u.x = bc_u(pk(f0.x, f0.y));
        u.y = bc_u(pk(f1.x, f1.y));
        u.z = bc_u(pk(f2.x, f2.y));
        u.w = bc_u(pk(f3.x, f3.y));
        wlds[g][t] = u;
    }
    hsmem[t] = (_Float16)0.0f;
    const float bias = b2[t];
    float* po = out + (size_t)b * HH + t;
    float hn = 0.0f;
    __syncthreads();

    for (int step = 0; step < SS; ++step) {
        float xpv = *po;   // issued early; consumed after the dot chain
        float acc = 0.0f;
#pragma unroll
        for (int g = 0; g < 48; g++) {
            uint4 hv = hs4[g];
            acc = fdot2(wr[4 * g + 0], bc_h2(hv.x), acc);
            acc = fdot2(wr[4 * g + 1], bc_h2(hv.y), acc);
            acc = fdot2(wr[4 * g + 2], bc_h2(hv.z), acc);
            acc = fdot2(wr[4 * g + 3], bc_h2(hv.w), acc);
        }
#pragma unroll
        for (int g = 0; g < 16; g++) {
            uint4 hv = hs4[48 + g];
            uint4 wv = wlds[g][t];
            acc = fdot2(bc_h2(wv.x), bc_h2(hv.x), acc);
            acc = fdot2(bc_h2(wv.y), bc_h2(hv.y), acc);
            acc = fdot2(bc_h2(wv.z), bc_h2(hv.z), acc);
            acc = fdot2(bc_h2(wv.w), bc_h2(hv.w), acc);
        }
        float z = acc + bias + xpv;
        hn = tanhf(z);
        *po = hn;
        __syncthreads();            // all reads of hsmem for this step done
        hsmem[t] = (_Float16)hn;
        __syncthreads();            // new h visible to all waves
        po += BB * HH;
    }
    hlast[(size_t)b * HH + t] = hn;
}

extern "C" void kernel_launch(void* const* d_in, const int* in_sizes, int n_in,
                              void* d_out, int out_size, void* d_ws, size_t ws_size,
                              hipStream_t stream) {
    const float* x  = (const float*)d_in[0];
    const float* W1 = (const float*)d_in[1];
    const float* b1 = (const float*)d_in[2];
    const float* W2 = (const float*)d_in[3];
    const float* b2 = (const float*)d_in[4];
    float* out = (float*)d_out;

    k_ingemm<<<dim3(MM / 64, HH / 64), 256, 0, stream>>>(x, W1, b1, out);
    k_rec3<<<BB, 512, 0, stream>>>(W2, b2, out, out + (size_t)SS * BB * HH);
}

// Round 5
// 1333.936 us; speedup vs baseline: 7.1827x; 1.3049x over previous
//
#include <hip/hip_runtime.h>
#include <math.h>

#define SS 512
#define BB 64
#define II 512
#define HH 512
#define MM (SS*BB)

typedef _Float16 h2 __attribute__((ext_vector_type(2)));

__device__ __forceinline__ float fdot2(h2 a, h2 b, float c) {
    return __builtin_amdgcn_fdot2(a, b, c, false);
}
__device__ __forceinline__ h2 bc_h2(unsigned int u) {
    return __builtin_bit_cast(h2, u);
}
__device__ __forceinline__ unsigned int bc_u(h2 v) {
    return __builtin_bit_cast(unsigned int, v);
}
// cvt_pkrtz returns __fp16 ext_vector(2); bit_cast it to our h2.
__device__ __forceinline__ h2 pk(float x, float y) {
    return __builtin_bit_cast(h2, __builtin_amdgcn_cvt_pkrtz(x, y));
}

// ---------------------------------------------------------------------------
// Input projection: C[m, j] = sum_k X[m,k] * W1[j,k] + b1[j]  (fp32 VALU GEMM)
// Writes xp directly into d_out's h_seq region (consumed in place later).
// ---------------------------------------------------------------------------
__global__ __launch_bounds__(256) void k_ingemm(const float* __restrict__ X,
                                                const float* __restrict__ W1,
                                                const float* __restrict__ b1,
                                                float* __restrict__ C) {
    __shared__ float As[16][64];
    __shared__ float Bs[16][64];
    const int bm = blockIdx.x * 64, bn = blockIdx.y * 64;
    const int tid = threadIdx.x;
    const int tm = (tid >> 4) << 2, tn = (tid & 15) << 2;
    const int lr = tid >> 2, lq = (tid & 3) << 2;
    float acc[4][4] = {};
    const float* Xp = X + (size_t)(bm + lr) * II + lq;
    const float* Wp = W1 + (size_t)(bn + lr) * II + lq;
    for (int kb = 0; kb < II; kb += 16) {
        float4 a = *(const float4*)(Xp + kb);
        float4 w = *(const float4*)(Wp + kb);
        As[lq + 0][lr] = a.x; As[lq + 1][lr] = a.y;
        As[lq + 2][lr] = a.z; As[lq + 3][lr] = a.w;
        Bs[lq + 0][lr] = w.x; Bs[lq + 1][lr] = w.y;
        Bs[lq + 2][lr] = w.z; Bs[lq + 3][lr] = w.w;
        __syncthreads();
#pragma unroll
        for (int k = 0; k < 16; k++) {
            float4 av = *(const float4*)&As[k][tm];
            float4 bv = *(const float4*)&Bs[k][tn];
            float aa[4] = {av.x, av.y, av.z, av.w};
            float bb[4] = {bv.x, bv.y, bv.z, bv.w};
#pragma unroll
            for (int i = 0; i < 4; i++)
#pragma unroll
                for (int j = 0; j < 4; j++)
                    acc[i][j] = fmaf(aa[i], bb[j], acc[i][j]);
        }
        __syncthreads();
    }
#pragma unroll
    for (int i = 0; i < 4; i++) {
        float4 bv = *(const float4*)&b1[bn + tn];
        float4 o;
        o.x = acc[i][0] + bv.x; o.y = acc[i][1] + bv.y;
        o.z = acc[i][2] + bv.z; o.w = acc[i][3] + bv.w;
        *(float4*)&C[(size_t)(bm + tm + i) * HH + bn + tn] = o;
    }
}

// ---------------------------------------------------------------------------
// Recurrence, W2 CU-resident in f16, h distributed via readlane (NOT LDS
// broadcast):
//   64 WGs (one per batch element) x 512 threads (8 waves, 1 WG/CU by LDS).
//   Thread t owns output column t: z[t] = sum_k W2[t][k] h[k].
//   k in [0,384): 192 packed f16-pairs in VGPRs.
//   k in [384,512): 128 KB LDS wlds[g][t] (uint4), per-lane 16B reads.
//   h exchange per step: h (512 f16 = 1 KB) sits in LDS; each wave does ONE
//   per-lane ds_read_b128 (lane L gets pairs 4L..4L+3), then v_readlane
//   broadcasts pair p from lane p>>2 comp p&3 into an SGPR consumed directly
//   by v_dot2_f32_f16 (VOP3P: 1 SGPR src is legal). LDS instrs/thread/step:
//   80 -> 17.
//   amdgpu_waves_per_eu(2,2): LDS caps us at 1 WG/CU anyway; pin occupancy so
//   the allocator uses the full 256-VGPR budget instead of spilling to AGPR.
// ---------------------------------------------------------------------------
__global__ __attribute__((amdgpu_flat_work_group_size(512, 512)))
__attribute__((amdgpu_waves_per_eu(2, 2)))
void k_rec4(const float* __restrict__ W2,
            const float* __restrict__ b2,
            float* __restrict__ out,
            float* __restrict__ hlast) {
    const int b = blockIdx.x;
    const int t = threadIdx.x;
    const int lane = t & 63;
    __shared__ uint4 wlds[16][512];                 // 128 KB
    __shared__ __align__(16) _Float16 hsmem[HH];    // 1 KB
    const uint4* hs4 = (const uint4*)hsmem;

    // One-time: load W2 row t, convert to packed f16 pairs.
    h2 wr[192];
    const float2* wrow = (const float2*)(W2 + (size_t)t * HH);
#pragma unroll
    for (int i = 0; i < 192; i++) {
        float2 f = wrow[i];
        wr[i] = pk(f.x, f.y);
    }
#pragma unroll
    for (int g = 0; g < 16; g++) {
        float2 f0 = wrow[192 + 4 * g + 0];
        float2 f1 = wrow[192 + 4 * g + 1];
        float2 f2 = wrow[192 + 4 * g + 2];
        float2 f3 = wrow[192 + 4 * g + 3];
        uint4 u;
        u.x = bc_u(pk(f0.x, f0.y));
        u.y = bc_u(pk(f1.x, f1.y));
        u.z = bc_u(pk(f2.x, f2.y));
        u.w = bc_u(pk(f3.x, f3.y));
        wlds[g][t] = u;
    }
    hsmem[t] = (_Float16)0.0f;
    const float bias = b2[t];
    float* po = out + (size_t)b * HH + t;
    float hn = 0.0f;
    __syncthreads();

    for (int step = 0; step < SS; ++step) {
        float xpv = *po;            // issued early; consumed after dot chain

        // One per-lane 16B read: lane L holds h-pairs 4L..4L+3 in hv.x..hv.w.
        uint4 hv = hs4[lane];

        float acc0 = 0.0f, acc1 = 0.0f;
        // k in [0,384): pairs 0..191, sourced from lanes 0..47 via readlane.
#pragma unroll
        for (int g = 0; g < 48; g++) {
            unsigned p0 = (unsigned)__builtin_amdgcn_readlane((int)hv.x, g);
            unsigned p1 = (unsigned)__builtin_amdgcn_readlane((int)hv.y, g);
            unsigned p2 = (unsigned)__builtin_amdgcn_readlane((int)hv.z, g);
            unsigned p3 = (unsigned)__builtin_amdgcn_readlane((int)hv.w, g);
            acc0 = fdot2(wr[4 * g + 0], bc_h2(p0), acc0);
            acc1 = fdot2(wr[4 * g + 1], bc_h2(p1), acc1);
            acc0 = fdot2(wr[4 * g + 2], bc_h2(p2), acc0);
            acc1 = fdot2(wr[4 * g + 3], bc_h2(p3), acc1);
        }
        // k in [384,512): pairs 192..255 from lanes 48..63; W2 slice from LDS.
#pragma unroll
        for (int g = 0; g < 16; g++) {
            uint4 wv = wlds[g][t];
            unsigned p0 = (unsigned)__builtin_amdgcn_readlane((int)hv.x, 48 + g);
            unsigned p1 = (unsigned)__builtin_amdgcn_readlane((int)hv.y, 48 + g);
            unsigned p2 = (unsigned)__builtin_amdgcn_readlane((int)hv.z, 48 + g);
            unsigned p3 = (unsigned)__builtin_amdgcn_readlane((int)hv.w, 48 + g);
            acc0 = fdot2(bc_h2(wv.x), bc_h2(p0), acc0);
            acc1 = fdot2(bc_h2(wv.y), bc_h2(p1), acc1);
            acc0 = fdot2(bc_h2(wv.z), bc_h2(p2), acc0);
            acc1 = fdot2(bc_h2(wv.w), bc_h2(p3), acc1);
        }
        float z = acc0 + acc1 + bias + xpv;
        hn = tanhf(z);
        *po = hn;
        __syncthreads();            // all hv gathers of this step complete
        hsmem[t] = (_Float16)hn;
        __syncthreads();            // new h visible to all waves
        po += BB * HH;
    }
    hlast[(size_t)b * HH + t] = hn;
}

extern "C" void kernel_launch(void* const* d_in, const int* in_sizes, int n_in,
                              void* d_out, int out_size, void* d_ws, size_t ws_size,
                              hipStream_t stream) {
    const float* x  = (const float*)d_in[0];
    const float* W1 = (const float*)d_in[1];
    const float* b1 = (const float*)d_in[2];
    const float* W2 = (const float*)d_in[3];
    const float* b2 = (const float*)d_in[4];
    float* out = (float*)d_out;

    k_ingemm<<<dim3(MM / 64, HH / 64), 256, 0, stream>>>(x, W1, b1, out);
    k_rec4<<<BB, 512, 0, stream>>>(W2, b2, out, out + (size_t)SS * BB * HH);
}

// Round 6
// 1072.368 us; speedup vs baseline: 8.9346x; 1.2439x over previous
//
#include <hip/hip_runtime.h>
#include <math.h>

#define SS 512
#define BB 64
#define II 512
#define HH 512
#define MM (SS*BB)

typedef _Float16 h2 __attribute__((ext_vector_type(2)));

__device__ __forceinline__ float fdot2(h2 a, h2 b, float c) {
    return __builtin_amdgcn_fdot2(a, b, c, false);
}
__device__ __forceinline__ h2 bc_h2(unsigned int u) {
    return __builtin_bit_cast(h2, u);
}
__device__ __forceinline__ unsigned int bc_u(h2 v) {
    return __builtin_bit_cast(unsigned int, v);
}
__device__ __forceinline__ h2 pk(float x, float y) {
    return __builtin_bit_cast(h2, __builtin_amdgcn_cvt_pkrtz(x, y));
}

// ---------------------------------------------------------------------------
// Input projection: C[m, j] = sum_k X[m,k] * W1[j,k] + b1[j]  (fp32 VALU GEMM)
// ---------------------------------------------------------------------------
__global__ __launch_bounds__(256) void k_ingemm(const float* __restrict__ X,
                                                const float* __restrict__ W1,
                                                const float* __restrict__ b1,
                                                float* __restrict__ C) {
    __shared__ float As[16][64];
    __shared__ float Bs[16][64];
    const int bm = blockIdx.x * 64, bn = blockIdx.y * 64;
    const int tid = threadIdx.x;
    const int tm = (tid >> 4) << 2, tn = (tid & 15) << 2;
    const int lr = tid >> 2, lq = (tid & 3) << 2;
    float acc[4][4] = {};
    const float* Xp = X + (size_t)(bm + lr) * II + lq;
    const float* Wp = W1 + (size_t)(bn + lr) * II + lq;
    for (int kb = 0; kb < II; kb += 16) {
        float4 a = *(const float4*)(Xp + kb);
        float4 w = *(const float4*)(Wp + kb);
        As[lq + 0][lr] = a.x; As[lq + 1][lr] = a.y;
        As[lq + 2][lr] = a.z; As[lq + 3][lr] = a.w;
        Bs[lq + 0][lr] = w.x; Bs[lq + 1][lr] = w.y;
        Bs[lq + 2][lr] = w.z; Bs[lq + 3][lr] = w.w;
        __syncthreads();
#pragma unroll
        for (int k = 0; k < 16; k++) {
            float4 av = *(const float4*)&As[k][tm];
            float4 bv = *(const float4*)&Bs[k][tn];
            float aa[4] = {av.x, av.y, av.z, av.w};
            float bb[4] = {bv.x, bv.y, bv.z, bv.w};
#pragma unroll
            for (int i = 0; i < 4; i++)
#pragma unroll
                for (int j = 0; j < 4; j++)
                    acc[i][j] = fmaf(aa[i], bb[j], acc[i][j]);
        }
        __syncthreads();
    }
#pragma unroll
    for (int i = 0; i < 4; i++) {
        float4 bv = *(const float4*)&b1[bn + tn];
        float4 o;
        o.x = acc[i][0] + bv.x; o.y = acc[i][1] + bv.y;
        o.z = acc[i][2] + bv.z; o.w = acc[i][3] + bv.w;
        *(float4*)&C[(size_t)(bm + tm + i) * HH + bn + tn] = o;
    }
}

// ---------------------------------------------------------------------------
// Recurrence, W2 CU-resident f16, COLUMN-BLOCKED to cut h-redistribution:
//   64 WGs x 512 threads (1 WG/CU). Thread t: cols c4 = (t&127)*4 .. c4+3,
//   k-chunk kk = t>>7 (k in [128kk,128kk+128) = 64 pairs, wave-uniform kk).
//   W2 slices: cols c4+0..2 in regs (3x64 = 192 pairs), col c4+3 in 128KB LDS.
//   h exchange: one conflict-free ds_read_b32 (lane L -> pair 64kk+L), then 64
//   immediate-lane readlanes per wave (vs 256 before; the unfolded v_mov per
//   pair was the round-5 cost driver, 1080 instr/thread/step measured).
//   Partial combine: part[kk][col] f32 — write = 1x ds_write_b128 stride-16B
//   (conflict-free), combine = 4x ds_read_b32 stride-4B (2 lanes/bank, free).
//   2 barriers/step: A (partials visible, h-reads drained), B (new h visible).
// ---------------------------------------------------------------------------
__global__ __attribute__((amdgpu_flat_work_group_size(512, 512)))
__attribute__((amdgpu_waves_per_eu(2, 2)))
void k_rec5(const float* __restrict__ W2,
            const float* __restrict__ b2,
            float* __restrict__ out,
            float* __restrict__ hlast) {
    const int b = blockIdx.x;
    const int t = threadIdx.x;
    const int lane = t & 63;
    const int kk = t >> 7;              // 0..3, wave-uniform
    const int c4 = (t & 127) << 2;      // base output column

    __shared__ uint4 wlds[16][512];                 // 128 KB: col c4+3 slices
    __shared__ float part[4][512];                  // 8 KB partial sums
    __shared__ __align__(16) _Float16 hsmem[HH];    // 1 KB h (f16)
    const unsigned* hs32 = (const unsigned*)hsmem;

    // ---- one-time init: pack W2 slices ----
    h2 wr0[64], wr1[64], wr2[64];
    {
        const float2* w0 = (const float2*)(W2 + (size_t)(c4 + 0) * HH) + (kk << 6);
        const float2* w1 = (const float2*)(W2 + (size_t)(c4 + 1) * HH) + (kk << 6);
        const float2* w2 = (const float2*)(W2 + (size_t)(c4 + 2) * HH) + (kk << 6);
#pragma unroll
        for (int g = 0; g < 64; g++) {
            float2 f0 = w0[g], f1 = w1[g], f2 = w2[g];
            wr0[g] = pk(f0.x, f0.y);
            wr1[g] = pk(f1.x, f1.y);
            wr2[g] = pk(f2.x, f2.y);
        }
        const float2* w3 = (const float2*)(W2 + (size_t)(c4 + 3) * HH) + (kk << 6);
#pragma unroll
        for (int g4 = 0; g4 < 16; g4++) {
            float2 f0 = w3[4 * g4 + 0], f1 = w3[4 * g4 + 1];
            float2 f2 = w3[4 * g4 + 2], f3 = w3[4 * g4 + 3];
            uint4 u;
            u.x = bc_u(pk(f0.x, f0.y));
            u.y = bc_u(pk(f1.x, f1.y));
            u.z = bc_u(pk(f2.x, f2.y));
            u.w = bc_u(pk(f3.x, f3.y));
            wlds[g4][t] = u;
        }
    }
    hsmem[t] = (_Float16)0.0f;
    const float bias = b2[t];
    float* po = out + (size_t)b * HH + t;
    float hn = 0.0f;
    __syncthreads();

    for (int step = 0; step < SS; ++step) {
        float xpv = *po;  // issued early, consumed in combine

        // lane L holds h-pair (64*kk + L); readlane g -> pair 64*kk+g.
        unsigned hv = hs32[(kk << 6) + lane];

        float a0 = 0.f, a1 = 0.f, a2 = 0.f, a3 = 0.f;
#pragma unroll
        for (int g4 = 0; g4 < 16; g4++) {
            uint4 wv = wlds[g4][t];
            unsigned wv4[4] = {wv.x, wv.y, wv.z, wv.w};
#pragma unroll
            for (int gg = 0; gg < 4; gg++) {
                const int g = 4 * g4 + gg;
                unsigned p = (unsigned)__builtin_amdgcn_readlane((int)hv, g);
                h2 hp = bc_h2(p);
                a0 = fdot2(wr0[g], hp, a0);
                a1 = fdot2(wr1[g], hp, a1);
                a2 = fdot2(wr2[g], hp, a2);
                a3 = fdot2(bc_h2(wv4[gg]), hp, a3);
            }
        }
        *(float4*)&part[kk][c4] = make_float4(a0, a1, a2, a3);
        __syncthreads();  // A: partials visible; all hv reads drained

        float z = part[0][t] + part[1][t] + part[2][t] + part[3][t] + bias + xpv;
        hn = tanhf(z);
        hsmem[t] = (_Float16)hn;
        *po = hn;
        po += BB * HH;
        __syncthreads();  // B: new h visible; part safe to overwrite
    }
    hlast[(size_t)b * HH + t] = hn;
}

extern "C" void kernel_launch(void* const* d_in, const int* in_sizes, int n_in,
                              void* d_out, int out_size, void* d_ws, size_t ws_size,
                              hipStream_t stream) {
    const float* x  = (const float*)d_in[0];
    const float* W1 = (const float*)d_in[1];
    const float* b1 = (const float*)d_in[2];
    const float* W2 = (const float*)d_in[3];
    const float* b2 = (const float*)d_in[4];
    float* out = (float*)d_out;

    k_ingemm<<<dim3(MM / 64, HH / 64), 256, 0, stream>>>(x, W1, b1, out);
    k_rec5<<<BB, 512, 0, stream>>>(W2, b2, out, out + (size_t)SS * BB * HH);
}

// Round 7
// 859.012 us; speedup vs baseline: 11.1538x; 1.2484x over previous
//
#include <hip/hip_runtime.h>
#include <math.h>

#define SS 512
#define BB 64
#define II 512
#define HH 512
#define MM (SS*BB)

typedef _Float16 h2 __attribute__((ext_vector_type(2)));
typedef _Float16 f16x8 __attribute__((ext_vector_type(8)));
typedef float f32x4 __attribute__((ext_vector_type(4)));

__device__ __forceinline__ h2 bc_h2(unsigned u) { return __builtin_bit_cast(h2, u); }
__device__ __forceinline__ unsigned bc_u(h2 v) { return __builtin_bit_cast(unsigned, v); }
__device__ __forceinline__ h2 pk(float x, float y) {
    return __builtin_bit_cast(h2, __builtin_amdgcn_cvt_pkrtz(x, y));
}

#if __has_builtin(__builtin_amdgcn_exp2f)
#define EXP2F __builtin_amdgcn_exp2f
#else
#define EXP2F exp2f
#endif
#if __has_builtin(__builtin_amdgcn_rcpf)
#define RCPF __builtin_amdgcn_rcpf
#else
#define RCPF(x) (1.0f / (x))
#endif

// branch-free tanh: tanh(z) = 1 - 2/(e^{2z}+1); exact at +-inf, err ~1e-6.
__device__ __forceinline__ float fast_tanh(float z) {
    float e = EXP2F(z * 2.885390081777927f);   // e^{2z} = 2^{2z*log2(e)}
    return 1.0f - 2.0f * RCPF(e + 1.0f);
}

// ---------------------------------------------------------------------------
// Input projection via f16 MFMA: C[m,j] = sum_k X[m,k]*W1[j,k] + b1[j].
// 128x128 tile, BK=32, 256 thr (4 waves, 2x2 of 64x64), f32 accumulate.
// LDS tiles XOR-swizzled (byte ^= (row&3)<<4) so ds_read_b128 frags are
// <=2-way bank aliased (free). Staging converts f32->f16 in-register.
// ---------------------------------------------------------------------------
__global__ __launch_bounds__(256) void k_ingemm2(const float* __restrict__ X,
                                                 const float* __restrict__ W1,
                                                 const float* __restrict__ b1,
                                                 float* __restrict__ C) {
    __shared__ __align__(16) _Float16 As[128 * 32];
    __shared__ __align__(16) _Float16 Bs[128 * 32];
    const int bm = blockIdx.x * 128;
    const int bn = blockIdx.y * 128;
    const int t = threadIdx.x;
    const int lane = t & 63;
    const int w = t >> 6;
    const int srow = t >> 1;             // staging row 0..127
    const int kb0 = (t & 1) * 32;        // staging k-byte base within row (64B)
    const int wm = (w >> 1) * 64, wn = (w & 1) * 64;

    f32x4 acc[4][4];
#pragma unroll
    for (int i = 0; i < 4; i++)
#pragma unroll
        for (int j = 0; j < 4; j++) acc[i][j] = f32x4{0.f, 0.f, 0.f, 0.f};

    const float* xs = X + (size_t)(bm + srow) * II + (t & 1) * 16;
    const float* ws = W1 + (size_t)(bn + srow) * II + (t & 1) * 16;
    char* asb = (char*)As + srow * 64;
    char* bsb = (char*)Bs + srow * 64;
    const int sw = (srow & 3) << 4;

    const int frow = lane & 15;          // fragment row/col within 16
    const int fkb = (lane >> 4) * 16;    // fragment k-byte base
    const int fsw = (frow & 3) << 4;     // matching XOR (row%4 is frow%4)

    for (int kt = 0; kt < 16; ++kt) {
        float4 a0 = *(const float4*)(xs + kt * 32 + 0);
        float4 a1 = *(const float4*)(xs + kt * 32 + 4);
        float4 a2 = *(const float4*)(xs + kt * 32 + 8);
        float4 a3 = *(const float4*)(xs + kt * 32 + 12);
        float4 c0 = *(const float4*)(ws + kt * 32 + 0);
        float4 c1 = *(const float4*)(ws + kt * 32 + 4);
        float4 c2 = *(const float4*)(ws + kt * 32 + 8);
        float4 c3 = *(const float4*)(ws + kt * 32 + 12);
        __syncthreads();   // previous iter's fragment reads complete
        uint4 u0, u1, v0, v1;
        u0.x = bc_u(pk(a0.x, a0.y)); u0.y = bc_u(pk(a0.z, a0.w));
        u0.z = bc_u(pk(a1.x, a1.y)); u0.w = bc_u(pk(a1.z, a1.w));
        u1.x = bc_u(pk(a2.x, a2.y)); u1.y = bc_u(pk(a2.z, a2.w));
        u1.z = bc_u(pk(a3.x, a3.y)); u1.w = bc_u(pk(a3.z, a3.w));
        v0.x = bc_u(pk(c0.x, c0.y)); v0.y = bc_u(pk(c0.z, c0.w));
        v0.z = bc_u(pk(c1.x, c1.y)); v0.w = bc_u(pk(c1.z, c1.w));
        v1.x = bc_u(pk(c2.x, c2.y)); v1.y = bc_u(pk(c2.z, c2.w));
        v1.z = bc_u(pk(c3.x, c3.y)); v1.w = bc_u(pk(c3.z, c3.w));
        *(uint4*)(asb + ((kb0 + 0) ^ sw)) = u0;
        *(uint4*)(asb + ((kb0 + 16) ^ sw)) = u1;
        *(uint4*)(bsb + ((kb0 + 0) ^ sw)) = v0;
        *(uint4*)(bsb + ((kb0 + 16) ^ sw)) = v1;
        __syncthreads();

        f16x8 af[4], bf[4];
#pragma unroll
        for (int i = 0; i < 4; i++) {
            const int ar = wm + 16 * i + frow;
            af[i] = *(const f16x8*)((const char*)As + ar * 64 + (fkb ^ fsw));
            const int br = wn + 16 * i + frow;
            bf[i] = *(const f16x8*)((const char*)Bs + br * 64 + (fkb ^ fsw));
        }
#pragma unroll
        for (int i = 0; i < 4; i++)
#pragma unroll
            for (int j = 0; j < 4; j++)
                acc[i][j] = __builtin_amdgcn_mfma_f32_16x16x32_f16(
                    af[i], bf[j], acc[i][j], 0, 0, 0);
    }

    // Epilogue: D layout col=lane&15, row=(lane>>4)*4+reg.
    const int erow = bm + wm + (lane >> 4) * 4;
    const int ecol = bn + wn + (lane & 15);
#pragma unroll
    for (int j = 0; j < 4; j++) {
        const float bj = b1[ecol + 16 * j];
#pragma unroll
        for (int i = 0; i < 4; i++)
#pragma unroll
            for (int r = 0; r < 4; r++)
                C[(size_t)(erow + 16 * i + r) * HH + ecol + 16 * j] =
                    acc[i][j][r] + bj;
    }
}

// ---------------------------------------------------------------------------
// Recurrence, W2 CU-resident f16, strided 8-col blocking + pk_fma:
//   64 WGs x 512 thr (8 waves). Wave w = k-chunk (k pairs [32w,32w+32));
//   lane L owns cols L+64*ci, ci=0..7 (strided -> part writes conflict-free).
//   ci 0..5 weights in regs (192 h2), ci 6,7 in 128KB LDS (16 uint4/thr/step).
//   h: one ds_read_b32/thr + 32 immediate readlanes (halved vs round 6).
//   MAC: h2 vector a = w*h + a -> v_pk_fma_f16, 2 chains/col (f16 accum over
//   32 pairs only; cross-chunk sums in f32 via part[8][512]).
//   2 barriers/step. LDS 145 KB.
// ---------------------------------------------------------------------------
__global__ __attribute__((amdgpu_flat_work_group_size(512, 512)))
__attribute__((amdgpu_waves_per_eu(2, 2)))
void k_rec6(const float* __restrict__ W2,
            const float* __restrict__ b2,
            float* __restrict__ out,
            float* __restrict__ hlast) {
    const int b = blockIdx.x;
    const int t = threadIdx.x;
    const int lane = t & 63;
    const int w = t >> 6;   // k-chunk = wave index (wave-uniform)

    __shared__ uint4 wlds[16][512];                  // 128 KB: cols ci=6,7
    __shared__ float part[8][512];                   // 16 KB partials
    __shared__ __align__(4) _Float16 hsmem[HH];      // 1 KB
    const unsigned* hs32 = (const unsigned*)hsmem;

    // one-time: pack W2 slices (col c = lane + 64*ci, k pairs [32w,32w+32))
    h2 wreg[6][32];
#pragma unroll
    for (int ci = 0; ci < 6; ci++) {
        const float2* src =
            (const float2*)(W2 + (size_t)(lane + 64 * ci) * HH) + (w << 5);
#pragma unroll
        for (int g = 0; g < 32; g++) wreg[ci][g] = pk(src[g].x, src[g].y);
    }
#pragma unroll
    for (int cc = 0; cc < 2; cc++) {
        const float2* src =
            (const float2*)(W2 + (size_t)(lane + 384 + 64 * cc) * HH) + (w << 5);
#pragma unroll
        for (int q = 0; q < 8; q++) {
            uint4 u;
            u.x = bc_u(pk(src[4 * q + 0].x, src[4 * q + 0].y));
            u.y = bc_u(pk(src[4 * q + 1].x, src[4 * q + 1].y));
            u.z = bc_u(pk(src[4 * q + 2].x, src[4 * q + 2].y));
            u.w = bc_u(pk(src[4 * q + 3].x, src[4 * q + 3].y));
            wlds[cc * 8 + q][t] = u;
        }
    }
    hsmem[t] = (_Float16)0.0f;
    const float bias = b2[t];
    float* po = out + (size_t)b * HH + t;
    float hn = 0.0f;
    __syncthreads();

    for (int step = 0; step < SS; ++step) {
        float xpv = *po;                       // early; used in combine
        unsigned hv = hs32[(w << 5) + (lane & 31)];  // lane L: pair 32w+L

        h2 accA[8], accB[8];
#pragma unroll
        for (int c = 0; c < 8; c++) { accA[c] = h2{0, 0}; accB[c] = h2{0, 0}; }

#pragma unroll
        for (int q = 0; q < 8; q++) {
            uint4 u6 = wlds[q][t];
            uint4 u7 = wlds[8 + q][t];
            unsigned w6[4] = {u6.x, u6.y, u6.z, u6.w};
            unsigned w7[4] = {u7.x, u7.y, u7.z, u7.w};
#pragma unroll
            for (int gg = 0; gg < 4; gg++) {
                const int g = 4 * q + gg;
                h2 hp = bc_h2((unsigned)__builtin_amdgcn_readlane((int)hv, g));
                if (gg & 1) {
                    accB[0] += wreg[0][g] * hp;
                    accB[1] += wreg[1][g] * hp;
                    accB[2] += wreg[2][g] * hp;
                    accB[3] += wreg[3][g] * hp;
                    accB[4] += wreg[4][g] * hp;
                    accB[5] += wreg[5][g] * hp;
                    accB[6] += bc_h2(w6[gg]) * hp;
                    accB[7] += bc_h2(w7[gg]) * hp;
                } else {
                    accA[0] += wreg[0][g] * hp;
                    accA[1] += wreg[1][g] * hp;
                    accA[2] += wreg[2][g] * hp;
                    accA[3] += wreg[3][g] * hp;
                    accA[4] += wreg[4][g] * hp;
                    accA[5] += wreg[5][g] * hp;
                    accA[6] += bc_h2(w6[gg]) * hp;
                    accA[7] += bc_h2(w7[gg]) * hp;
                }
            }
        }
#pragma unroll
        for (int c = 0; c < 8; c++) {
            h2 s = accA[c] + accB[c];
            part[w][lane + 64 * c] = (float)s.x + (float)s.y;  // conflict-free
        }
        __syncthreads();  // A: partials visible; h reads drained

        float z = part[0][t] + part[1][t] + part[2][t] + part[3][t] +
                  part[4][t] + part[5][t] + part[6][t] + part[7][t] +
                  bias + xpv;
        hn = fast_tanh(z);
        hsmem[t] = (_Float16)hn;
        *po = hn;
        po += BB * HH;
        __syncthreads();  // B: new h visible; part safe to overwrite
    }
    hlast[(size_t)b * HH + t] = hn;
}

extern "C" void kernel_launch(void* const* d_in, const int* in_sizes, int n_in,
                              void* d_out, int out_size, void* d_ws, size_t ws_size,
                              hipStream_t stream) {
    const float* x  = (const float*)d_in[0];
    const float* W1 = (const float*)d_in[1];
    const float* b1 = (const float*)d_in[2];
    const float* W2 = (const float*)d_in[3];
    const float* b2 = (const float*)d_in[4];
    float* out = (float*)d_out;

    k_ingemm2<<<dim3(MM / 128, HH / 128), 256, 0, stream>>>(x, W1, b1, out);
    k_rec6<<<BB, 512, 0, stream>>>(W2, b2, out, out + (size_t)SS * BB * HH);
}